// Round 5
// baseline (646.505 us; speedup 1.0000x reference)
//
#include <hip/hip_runtime.h>
#include <math.h>

#define N_NODES 100000
#define N_EDGES 1600000
#define HID 64
#define SCAN_B 1024
#define NB ((N_NODES + SCAN_B - 1) / SCAN_B)   // 98 blocks
#define NPW 8    // nodes per wave in fused layer kernels

// ---------------- preamble: degree count (int4: 4 edges/thread) ----------------

__global__ void count4_kernel(const int* __restrict__ dst, int* __restrict__ deg) {
    int t = blockIdx.x * blockDim.x + threadIdx.x;
    if (t < N_EDGES / 4) {
        int4 d4 = ((const int4*)dst)[t];
        atomicAdd(&deg[d4.x], 1);
        atomicAdd(&deg[d4.y], 1);
        atomicAdd(&deg[d4.z], 1);
        atomicAdd(&deg[d4.w], 1);
    }
}

// ---------------- scan stage A (+ fused dinv) ----------------

__global__ void scan_block_kernel(const int* __restrict__ deg, int* __restrict__ rowptr,
                                  int* __restrict__ bsum, float* __restrict__ dinv) {
    __shared__ int wsum[16];
    int tid = threadIdx.x, lane = tid & 63, wid = tid >> 6;
    int i = blockIdx.x * SCAN_B + tid;
    int v = (i < N_NODES) ? deg[i] : 0;
    int x = v;
#pragma unroll
    for (int off = 1; off < 64; off <<= 1) {
        int y = __shfl_up(x, off, 64);
        if (lane >= off) x += y;
    }
    if (lane == 63) wsum[wid] = x;
    __syncthreads();
    if (tid == 0) {
        int s = 0;
#pragma unroll
        for (int j = 0; j < 16; ++j) { int t2 = wsum[j]; wsum[j] = s; s += t2; }
    }
    __syncthreads();
    int inc = wsum[wid] + x;
    if (i < N_NODES) {
        rowptr[i + 1] = inc;
        dinv[i] = rsqrtf(1.0f + (float)v);
    }
    if (tid == SCAN_B - 1) bsum[blockIdx.x] = inc;
}

__global__ void scan_bsum_kernel(int* __restrict__ bsum) {
    __shared__ int tmp[128];
    int t = threadIdx.x;
    tmp[t] = (t < NB) ? bsum[t] : 0;
    __syncthreads();
    for (int off = 1; off < 128; off <<= 1) {
        int v = (t >= off) ? tmp[t - off] : 0;
        __syncthreads();
        tmp[t] += v;
        __syncthreads();
    }
    if (t < NB) bsum[t] = (t == 0) ? 0 : tmp[t - 1];
}

__global__ void add_off_kernel(int* __restrict__ rowptr, const int* __restrict__ bsum) {
    int i = blockIdx.x * SCAN_B + threadIdx.x;
    if (i == 0) rowptr[0] = 0;
    if (i < N_NODES) rowptr[i + 1] += bsum[blockIdx.x];
}

// ---------------- CSR fill (int4: 4 edges/thread) ----------------

__global__ void fill4_kernel(const int* __restrict__ src, const int* __restrict__ dst,
                             const int* __restrict__ rowptr, int* __restrict__ cursor,
                             int* __restrict__ csr_src) {
    int t = blockIdx.x * blockDim.x + threadIdx.x;
    if (t < N_EDGES / 4) {
        int4 s4 = ((const int4*)src)[t];
        int4 d4 = ((const int4*)dst)[t];
        int p0 = rowptr[d4.x] + atomicAdd(&cursor[d4.x], 1);
        csr_src[p0] = s4.x;
        int p1 = rowptr[d4.y] + atomicAdd(&cursor[d4.y], 1);
        csr_src[p1] = s4.y;
        int p2 = rowptr[d4.z] + atomicAdd(&cursor[d4.z], 1);
        csr_src[p2] = s4.z;
        int p3 = rowptr[d4.w] + atomicAdd(&cursor[d4.w], 1);
        csr_src[p3] = s4.w;
    }
}

// ---------------- layer 1: g = dinv * (x @ W1) ----------------

__global__ void layer1_kernel(const float* __restrict__ x, const float* __restrict__ W1,
                              const float* __restrict__ dinv, float* __restrict__ g) {
    int idx = blockIdx.x * blockDim.x + threadIdx.x;
    if (idx >= N_NODES * HID) return;
    int n = idx >> 6, c = idx & 63;
    float v = x[n * 3 + 0] * W1[0 * HID + c] + x[n * 3 + 1] * W1[1 * HID + c]
            + x[n * 3 + 2] * W1[2 * HID + c];
    g[idx] = v * dinv[n];
}

// ---------------- fused layer: float4 gather (16 lanes/edge) + matmul ----------------
// Gather: lane group q=lane>>4 handles edge j0+q (+4,+8,+12); one wave-load
// covers 4 edges (1 KB), indices are 16-lane-broadcast dword loads, no shfl.
// Cross-group combine: 8 butterfly shfls. Matmul: W column in VGPRs (float4
// Wr[16]), hv via 16 same-addr ds_read_b128 broadcasts, 4 accumulators.

__device__ __forceinline__ float4 gather4(const float4* __restrict__ g4,
                                          const int* __restrict__ csr,
                                          int beg, int end, int q, int p,
                                          float4 acc) {
    for (int j0 = beg; j0 < end; j0 += 16) {
        int jA = j0 + q;
        int jB = jA + 4, jC = jA + 8, jD = jA + 12;
        if (jA < end) { int s = csr[jA]; float4 v = g4[s * 16 + p];
                        acc.x += v.x; acc.y += v.y; acc.z += v.z; acc.w += v.w; }
        if (jB < end) { int s = csr[jB]; float4 v = g4[s * 16 + p];
                        acc.x += v.x; acc.y += v.y; acc.z += v.z; acc.w += v.w; }
        if (jC < end) { int s = csr[jC]; float4 v = g4[s * 16 + p];
                        acc.x += v.x; acc.y += v.y; acc.z += v.z; acc.w += v.w; }
        if (jD < end) { int s = csr[jD]; float4 v = g4[s * 16 + p];
                        acc.x += v.x; acc.y += v.y; acc.z += v.z; acc.w += v.w; }
    }
    return acc;
}

__global__ __launch_bounds__(256, 4)
void agg_layer_kernel(const float* __restrict__ g_in, const int* __restrict__ rowptr,
                      const int* __restrict__ csr, const float* __restrict__ dinv,
                      const float* __restrict__ bprev, const float* __restrict__ W,
                      float* __restrict__ g_out) {
    __shared__ float hvbuf[4][HID];
    const int lane = threadIdx.x & 63, wid = threadIdx.x >> 6;
    const int q = lane >> 4, p = lane & 15;
    const float4* g4 = (const float4*)g_in;
    float4 Wr[16];
#pragma unroll
    for (int kk = 0; kk < 16; ++kk)
        Wr[kk] = make_float4(W[(4 * kk + 0) * HID + lane], W[(4 * kk + 1) * HID + lane],
                             W[(4 * kk + 2) * HID + lane], W[(4 * kk + 3) * HID + lane]);
    const float4 b4 = ((const float4*)bprev)[p];
    float* hvp = &hvbuf[wid][0];
    const float4* hp4 = (const float4*)hvp;
    float4* hvw4 = (float4*)hvp;
    int n0 = (blockIdx.x * 4 + wid) * NPW;
    int nend = min(n0 + NPW, N_NODES);
    for (int n = n0; n < nend; ++n) {
        int beg = rowptr[n], end = rowptr[n + 1];
        float4 acc = make_float4(0.f, 0.f, 0.f, 0.f);
        if (lane < 16) acc = g4[n * 16 + p];   // self-loop on group 0
        acc = gather4(g4, csr, beg, end, q, p, acc);
#pragma unroll
        for (int off = 32; off >= 16; off >>= 1) {
            acc.x += __shfl_xor(acc.x, off, 64);
            acc.y += __shfl_xor(acc.y, off, 64);
            acc.z += __shfl_xor(acc.z, off, 64);
            acc.w += __shfl_xor(acc.w, off, 64);
        }
        float di = dinv[n];
        float4 hv;
        hv.x = fmaxf(di * acc.x + b4.x, 0.0f);
        hv.y = fmaxf(di * acc.y + b4.y, 0.0f);
        hv.z = fmaxf(di * acc.z + b4.z, 0.0f);
        hv.w = fmaxf(di * acc.w + b4.w, 0.0f);
        if (lane < 16) hvw4[p] = hv;
        float r0 = 0.f, r1 = 0.f, r2 = 0.f, r3 = 0.f;
#pragma unroll
        for (int kk = 0; kk < 16; ++kk) {
            float4 h4 = hp4[kk];   // same addr across lanes -> broadcast
            r0 = fmaf(h4.x, Wr[kk].x, r0);
            r1 = fmaf(h4.y, Wr[kk].y, r1);
            r2 = fmaf(h4.z, Wr[kk].z, r2);
            r3 = fmaf(h4.w, Wr[kk].w, r3);
        }
        g_out[n * HID + lane] = di * ((r0 + r1) + (r2 + r3));
    }
}

__global__ __launch_bounds__(256, 4)
void final_kernel(const float* __restrict__ g_in, const int* __restrict__ rowptr,
                  const int* __restrict__ csr, const float* __restrict__ dinv,
                  const float* __restrict__ b3, const float* __restrict__ Wm1,
                  const float* __restrict__ bm1, const float* __restrict__ Wm2,
                  const float* __restrict__ bm2, float* __restrict__ out) {
    __shared__ float hvbuf[4][HID];
    const int lane = threadIdx.x & 63, wid = threadIdx.x >> 6;
    const int q = lane >> 4, p = lane & 15;
    const float4* g4 = (const float4*)g_in;
    float4 Wr[16];
#pragma unroll
    for (int kk = 0; kk < 16; ++kk)
        Wr[kk] = make_float4(Wm1[(4 * kk + 0) * HID + lane], Wm1[(4 * kk + 1) * HID + lane],
                             Wm1[(4 * kk + 2) * HID + lane], Wm1[(4 * kk + 3) * HID + lane]);
    const float4 b4 = ((const float4*)b3)[p];
    float bm1l = bm1[lane];
    float wm2l = Wm2[lane];
    float bm20 = bm2[0];
    float* hvp = &hvbuf[wid][0];
    const float4* hp4 = (const float4*)hvp;
    float4* hvw4 = (float4*)hvp;
    int n0 = (blockIdx.x * 4 + wid) * NPW;
    int nend = min(n0 + NPW, N_NODES);
    for (int n = n0; n < nend; ++n) {
        int beg = rowptr[n], end = rowptr[n + 1];
        float4 acc = make_float4(0.f, 0.f, 0.f, 0.f);
        if (lane < 16) acc = g4[n * 16 + p];
        acc = gather4(g4, csr, beg, end, q, p, acc);
#pragma unroll
        for (int off = 32; off >= 16; off >>= 1) {
            acc.x += __shfl_xor(acc.x, off, 64);
            acc.y += __shfl_xor(acc.y, off, 64);
            acc.z += __shfl_xor(acc.z, off, 64);
            acc.w += __shfl_xor(acc.w, off, 64);
        }
        float di = dinv[n];
        float4 hv;
        hv.x = fmaxf(di * acc.x + b4.x, 0.0f);
        hv.y = fmaxf(di * acc.y + b4.y, 0.0f);
        hv.z = fmaxf(di * acc.z + b4.z, 0.0f);
        hv.w = fmaxf(di * acc.w + b4.w, 0.0f);
        if (lane < 16) hvw4[p] = hv;
        float r0 = 0.f, r1 = 0.f, r2 = 0.f, r3 = 0.f;
#pragma unroll
        for (int kk = 0; kk < 16; ++kk) {
            float4 h4 = hp4[kk];
            r0 = fmaf(h4.x, Wr[kk].x, r0);
            r1 = fmaf(h4.y, Wr[kk].y, r1);
            r2 = fmaf(h4.z, Wr[kk].z, r2);
            r3 = fmaf(h4.w, Wr[kk].w, r3);
        }
        float m = fmaxf(((r0 + r1) + (r2 + r3)) + bm1l, 0.0f);
        float s = m * wm2l;
#pragma unroll
        for (int off = 32; off > 0; off >>= 1) s += __shfl_down(s, off, 64);
        if (lane == 0) out[n] = 1.0f / (1.0f + expf(-(s + bm20)));
    }
}

// ---------------- launch ----------------

extern "C" void kernel_launch(void* const* d_in, const int* in_sizes, int n_in,
                              void* d_out, int out_size, void* d_ws, size_t ws_size,
                              hipStream_t stream) {
    const float* x   = (const float*)d_in[0];
    const int*   ei  = (const int*)d_in[1];
    const float* W1  = (const float*)d_in[2];
    const float* b1  = (const float*)d_in[3];
    const float* W2  = (const float*)d_in[4];
    const float* b2  = (const float*)d_in[5];
    const float* W3  = (const float*)d_in[6];
    const float* b3  = (const float*)d_in[7];
    const float* Wm1 = (const float*)d_in[8];
    const float* bm1 = (const float*)d_in[9];
    const float* Wm2 = (const float*)d_in[10];
    const float* bm2 = (const float*)d_in[11];
    float* out = (float*)d_out;

    const int* src = ei;
    const int* dst = ei + N_EDGES;

    char* ws = (char*)d_ws;
    size_t off = 0;
    auto alloc = [&](size_t bytes) { size_t o = off; off = (off + bytes + 255) & ~(size_t)255; return (void*)(ws + o); };
    int*   deg    = (int*)alloc(4ll * N_NODES + 4ll * N_NODES);  // deg + cursor, one memset
    int*   cursor = deg + N_NODES;
    int*   rowptr = (int*)alloc(4ll * (N_NODES + 1));
    int*   bsum   = (int*)alloc(4ll * NB);
    int*   csr    = (int*)alloc(4ll * N_EDGES);
    float* dinv   = (float*)alloc(4ll * N_NODES);
    float* gA     = (float*)alloc(4ll * N_NODES * HID);
    float* gB     = (float*)alloc(4ll * N_NODES * HID);
    (void)ws_size;

    // --- CSR build ---
    hipMemsetAsync(deg, 0, 8ll * N_NODES, stream);   // deg + cursor
    count4_kernel<<<(N_EDGES / 4 + 255) / 256, 256, 0, stream>>>(dst, deg);
    scan_block_kernel<<<NB, SCAN_B, 0, stream>>>(deg, rowptr, bsum, dinv);
    scan_bsum_kernel<<<1, 128, 0, stream>>>(bsum);
    add_off_kernel<<<NB, SCAN_B, 0, stream>>>(rowptr, bsum);
    fill4_kernel<<<(N_EDGES / 4 + 255) / 256, 256, 0, stream>>>(src, dst, rowptr, cursor, csr);

    // --- layers ---
    int nwaves = (N_NODES + NPW - 1) / NPW;      // 12500
    int nblocks = (nwaves + 3) / 4;              // 3125
    layer1_kernel<<<(N_NODES * HID + 255) / 256, 256, 0, stream>>>(x, W1, dinv, gA);
    agg_layer_kernel<<<nblocks, 256, 0, stream>>>(gA, rowptr, csr, dinv, b1, W2, gB);
    agg_layer_kernel<<<nblocks, 256, 0, stream>>>(gB, rowptr, csr, dinv, b2, W3, gA);
    final_kernel<<<nblocks, 256, 0, stream>>>(gA, rowptr, csr, dinv, b3, Wm1, bm1, Wm2, bm2, out);
}

// Round 6
// 533.832 us; speedup vs baseline: 1.2111x; 1.2111x over previous
//
#include <hip/hip_runtime.h>
#include <hip/hip_fp16.h>
#include <math.h>

#define N_NODES 100000
#define N_EDGES 1600000
#define HID 64
#define N16 (N_NODES * 16)                     // elements per feature-quarter
#define SCAN_B 1024
#define NB ((N_NODES + SCAN_B - 1) / SCAN_B)   // 98 blocks
#define NPG 8    // nodes per wave, gather kernel
#define NPW 4    // nodes per wave, transform kernels

// ---------------- preamble: degree count + per-edge rank (atomic return) ----------------

__global__ void count4_kernel(const int* __restrict__ dst, int* __restrict__ deg,
                              int* __restrict__ rank) {
    int t = blockIdx.x * blockDim.x + threadIdx.x;
    if (t < N_EDGES / 4) {
        int4 d4 = ((const int4*)dst)[t];
        int4 r;
        r.x = atomicAdd(&deg[d4.x], 1);
        r.y = atomicAdd(&deg[d4.y], 1);
        r.z = atomicAdd(&deg[d4.z], 1);
        r.w = atomicAdd(&deg[d4.w], 1);
        ((int4*)rank)[t] = r;
    }
}

// ---------------- scan (+ fused dinv) ----------------

__global__ void scan_block_kernel(const int* __restrict__ deg, int* __restrict__ rowptr,
                                  int* __restrict__ bsum, float* __restrict__ dinv) {
    __shared__ int wsum[16];
    int tid = threadIdx.x, lane = tid & 63, wid = tid >> 6;
    int i = blockIdx.x * SCAN_B + tid;
    int v = (i < N_NODES) ? deg[i] : 0;
    int x = v;
#pragma unroll
    for (int off = 1; off < 64; off <<= 1) {
        int y = __shfl_up(x, off, 64);
        if (lane >= off) x += y;
    }
    if (lane == 63) wsum[wid] = x;
    __syncthreads();
    if (tid == 0) {
        int s = 0;
#pragma unroll
        for (int j = 0; j < 16; ++j) { int t2 = wsum[j]; wsum[j] = s; s += t2; }
    }
    __syncthreads();
    int inc = wsum[wid] + x;
    if (i < N_NODES) {
        rowptr[i + 1] = inc;
        dinv[i] = rsqrtf(1.0f + (float)v);
    }
    if (tid == SCAN_B - 1) bsum[blockIdx.x] = inc;
}

__global__ void scan_bsum_kernel(int* __restrict__ bsum) {
    __shared__ int tmp[128];
    int t = threadIdx.x;
    tmp[t] = (t < NB) ? bsum[t] : 0;
    __syncthreads();
    for (int off = 1; off < 128; off <<= 1) {
        int v = (t >= off) ? tmp[t - off] : 0;
        __syncthreads();
        tmp[t] += v;
        __syncthreads();
    }
    if (t < NB) bsum[t] = (t == 0) ? 0 : tmp[t - 1];
}

__global__ void add_off_kernel(int* __restrict__ rowptr, const int* __restrict__ bsum) {
    int i = blockIdx.x * SCAN_B + threadIdx.x;
    if (i == 0) rowptr[0] = 0;
    if (i < N_NODES) rowptr[i + 1] += bsum[blockIdx.x];
}

// ---------------- CSR fill: no atomics (rank precomputed) ----------------

__global__ void fill4_kernel(const int* __restrict__ src, const int* __restrict__ dst,
                             const int* __restrict__ rank, const int* __restrict__ rowptr,
                             int* __restrict__ csr_src) {
    int t = blockIdx.x * blockDim.x + threadIdx.x;
    if (t < N_EDGES / 4) {
        int4 s4 = ((const int4*)src)[t];
        int4 d4 = ((const int4*)dst)[t];
        int4 r4 = ((const int4*)rank)[t];
        csr_src[rowptr[d4.x] + r4.x] = s4.x;
        csr_src[rowptr[d4.y] + r4.y] = s4.y;
        csr_src[rowptr[d4.z] + r4.z] = s4.z;
        csr_src[rowptr[d4.w] + r4.w] = s4.w;
    }
}

// ---------------- layer 1: g = dinv * (x @ W1) -> fp16 quarter-major ----------------

__global__ void layer1_kernel(const float* __restrict__ x, const float* __restrict__ W1,
                              const float* __restrict__ dinv, __half* __restrict__ gq) {
    int idx = blockIdx.x * blockDim.x + threadIdx.x;   // N*32 threads (2 features each)
    if (idx >= N_NODES * 32) return;
    int n = idx >> 5, cp = idx & 31;
    int c = cp << 1;
    float x0 = x[n * 3 + 0], x1 = x[n * 3 + 1], x2 = x[n * 3 + 2];
    float di = dinv[n];
    float v0 = (x0 * W1[c]     + x1 * W1[HID + c]     + x2 * W1[2 * HID + c])     * di;
    float v1 = (x0 * W1[c + 1] + x1 * W1[HID + c + 1] + x2 * W1[2 * HID + c + 1]) * di;
    *(__half2*)(gq + (size_t)(cp >> 3) * N16 + n * 16 + (c & 15)) = __floats2half2_rn(v0, v1);
}

// ---------------- gather: quarter-split, XCD-pinned via blockIdx&3 ----------------
// Wave: 8 edge-groups x 8 lanes; each group pulls one edge's 32B fp16 quarter.
// 2-way unrolled for 2 loads in flight; butterfly-xor combine across groups.

__global__ __launch_bounds__(256)
void gather_kernel(const __half* __restrict__ gq, const int* __restrict__ rowptr,
                   const int* __restrict__ csr, float* __restrict__ agg) {
    const int lane = threadIdx.x & 63, wid = threadIdx.x >> 6;
    const int q = blockIdx.x & 3;                 // quarter; round-robin XCD -> L2-resident
    const int eg = lane >> 3, p = lane & 7;
    const __half2* gq2 = (const __half2*)(gq + (size_t)q * N16);
    float* aggq = agg + (size_t)q * N16;
    int n0 = ((blockIdx.x >> 2) * 4 + wid) * NPG;
    int nend = min(n0 + NPG, N_NODES);
    for (int n = n0; n < nend; ++n) {
        int beg = rowptr[n], end = rowptr[n + 1];
        float2 acc = make_float2(0.f, 0.f);
        if (eg == 0) {                            // self-loop term
            float2 v = __half22float2(gq2[n * 8 + p]);
            acc.x = v.x; acc.y = v.y;
        }
        int j = beg + eg;
        for (; j + 8 < end; j += 16) {
            int sA = csr[j], sB = csr[j + 8];
            float2 vA = __half22float2(gq2[sA * 8 + p]);
            float2 vB = __half22float2(gq2[sB * 8 + p]);
            acc.x += vA.x + vB.x;
            acc.y += vA.y + vB.y;
        }
        if (j < end) {
            int s = csr[j];
            float2 v = __half22float2(gq2[s * 8 + p]);
            acc.x += v.x; acc.y += v.y;
        }
#pragma unroll
        for (int off = 8; off < 64; off <<= 1) {
            acc.x += __shfl_xor(acc.x, off, 64);
            acc.y += __shfl_xor(acc.y, off, 64);
        }
        if (eg == 0) ((float2*)(aggq + n * 16))[p] = acc;
    }
}

// ---------------- transform: hv = relu(di*agg + b); g_out = di*(hv @ W) fp16 ----------------

__global__ __launch_bounds__(256)
void transform_kernel(const float* __restrict__ agg, const float* __restrict__ dinv,
                      const float* __restrict__ bprev, const float* __restrict__ W,
                      __half* __restrict__ gq_out) {
    __shared__ float hvbuf[4][HID];
    const int lane = threadIdx.x & 63, wid = threadIdx.x >> 6;
    float4 Wr[16];
#pragma unroll
    for (int kk = 0; kk < 16; ++kk)
        Wr[kk] = make_float4(W[(4 * kk + 0) * HID + lane], W[(4 * kk + 1) * HID + lane],
                             W[(4 * kk + 2) * HID + lane], W[(4 * kk + 3) * HID + lane]);
    const float bl = bprev[lane];
    const int qr = lane >> 4, pos = lane & 15;
    const float* aggl = agg + (size_t)qr * N16 + pos;
    float* hvp = &hvbuf[wid][0];
    const float4* hp4 = (const float4*)hvp;
    int n0 = (blockIdx.x * 4 + wid) * NPW;
    int nend = min(n0 + NPW, N_NODES);
    for (int n = n0; n < nend; ++n) {
        float a = aggl[(size_t)n * 16];
        float di = dinv[n];
        float hv = fmaxf(fmaf(di, a, bl), 0.0f);
        hvp[lane] = hv;
        float r0 = 0.f, r1 = 0.f, r2 = 0.f, r3 = 0.f;
#pragma unroll
        for (int kk = 0; kk < 16; ++kk) {
            float4 h4 = hp4[kk];   // same addr across lanes -> broadcast
            r0 = fmaf(h4.x, Wr[kk].x, r0);
            r1 = fmaf(h4.y, Wr[kk].y, r1);
            r2 = fmaf(h4.z, Wr[kk].z, r2);
            r3 = fmaf(h4.w, Wr[kk].w, r3);
        }
        float r = di * ((r0 + r1) + (r2 + r3));
        float rn = __shfl_down(r, 1, 64);
        if (!(lane & 1)) {
            *(__half2*)(gq_out + (size_t)qr * N16 + n * 16 + pos) = __floats2half2_rn(r, rn);
        }
    }
}

// ---------------- final: hv = relu(di*agg + b3); MLP head + sigmoid ----------------

__global__ __launch_bounds__(256)
void final_kernel(const float* __restrict__ agg, const float* __restrict__ dinv,
                  const float* __restrict__ b3, const float* __restrict__ Wm1,
                  const float* __restrict__ bm1, const float* __restrict__ Wm2,
                  const float* __restrict__ bm2, float* __restrict__ out) {
    __shared__ float hvbuf[4][HID];
    const int lane = threadIdx.x & 63, wid = threadIdx.x >> 6;
    float4 Wr[16];
#pragma unroll
    for (int kk = 0; kk < 16; ++kk)
        Wr[kk] = make_float4(Wm1[(4 * kk + 0) * HID + lane], Wm1[(4 * kk + 1) * HID + lane],
                             Wm1[(4 * kk + 2) * HID + lane], Wm1[(4 * kk + 3) * HID + lane]);
    const float bl = b3[lane];
    const float bm1l = bm1[lane];
    const float wm2l = Wm2[lane];
    const float bm20 = bm2[0];
    const int qr = lane >> 4, pos = lane & 15;
    const float* aggl = agg + (size_t)qr * N16 + pos;
    float* hvp = &hvbuf[wid][0];
    const float4* hp4 = (const float4*)hvp;
    int n0 = (blockIdx.x * 4 + wid) * NPW;
    int nend = min(n0 + NPW, N_NODES);
    for (int n = n0; n < nend; ++n) {
        float a = aggl[(size_t)n * 16];
        float di = dinv[n];
        float hv = fmaxf(fmaf(di, a, bl), 0.0f);
        hvp[lane] = hv;
        float r0 = 0.f, r1 = 0.f, r2 = 0.f, r3 = 0.f;
#pragma unroll
        for (int kk = 0; kk < 16; ++kk) {
            float4 h4 = hp4[kk];
            r0 = fmaf(h4.x, Wr[kk].x, r0);
            r1 = fmaf(h4.y, Wr[kk].y, r1);
            r2 = fmaf(h4.z, Wr[kk].z, r2);
            r3 = fmaf(h4.w, Wr[kk].w, r3);
        }
        float m = fmaxf(((r0 + r1) + (r2 + r3)) + bm1l, 0.0f);
        float s = m * wm2l;
#pragma unroll
        for (int off = 32; off > 0; off >>= 1) s += __shfl_down(s, off, 64);
        if (lane == 0) out[n] = 1.0f / (1.0f + expf(-(s + bm20)));
    }
}

// ---------------- launch ----------------

extern "C" void kernel_launch(void* const* d_in, const int* in_sizes, int n_in,
                              void* d_out, int out_size, void* d_ws, size_t ws_size,
                              hipStream_t stream) {
    const float* x   = (const float*)d_in[0];
    const int*   ei  = (const int*)d_in[1];
    const float* W1  = (const float*)d_in[2];
    const float* b1  = (const float*)d_in[3];
    const float* W2  = (const float*)d_in[4];
    const float* b2  = (const float*)d_in[5];
    const float* W3  = (const float*)d_in[6];
    const float* b3  = (const float*)d_in[7];
    const float* Wm1 = (const float*)d_in[8];
    const float* bm1 = (const float*)d_in[9];
    const float* Wm2 = (const float*)d_in[10];
    const float* bm2 = (const float*)d_in[11];
    float* out = (float*)d_out;

    const int* src = ei;
    const int* dst = ei + N_EDGES;

    char* ws = (char*)d_ws;
    size_t off = 0;
    auto alloc = [&](size_t bytes) { size_t o = off; off = (off + bytes + 255) & ~(size_t)255; return (void*)(ws + o); };
    int*    deg    = (int*)alloc(4ll * N_NODES);
    int*    rowptr = (int*)alloc(4ll * (N_NODES + 1));
    int*    bsum   = (int*)alloc(4ll * NB);
    int*    rank   = (int*)alloc(4ll * N_EDGES);
    int*    csr    = (int*)alloc(4ll * N_EDGES);
    float*  dinv   = (float*)alloc(4ll * N_NODES);
    __half* gq     = (__half*)alloc(2ll * 4 * N16);   // fp16, quarter-major [4][N][16]
    float*  agg    = (float*)alloc(4ll * 4 * N16);    // fp32, quarter-major [4][N][16]
    (void)ws_size;

    // --- CSR build ---
    hipMemsetAsync(deg, 0, 4ll * N_NODES, stream);
    count4_kernel<<<(N_EDGES / 4 + 255) / 256, 256, 0, stream>>>(dst, deg, rank);
    scan_block_kernel<<<NB, SCAN_B, 0, stream>>>(deg, rowptr, bsum, dinv);
    scan_bsum_kernel<<<1, 128, 0, stream>>>(bsum);
    add_off_kernel<<<NB, SCAN_B, 0, stream>>>(rowptr, bsum);
    fill4_kernel<<<(N_EDGES / 4 + 255) / 256, 256, 0, stream>>>(src, dst, rank, rowptr, csr);

    // --- layers ---
    int gat_blocks = 4 * (((N_NODES + NPG - 1) / NPG + 3) / 4);  // 12500
    int tr_blocks  = ((N_NODES + NPW - 1) / NPW + 3) / 4;        // 6250
    layer1_kernel<<<(N_NODES * 32 + 255) / 256, 256, 0, stream>>>(x, W1, dinv, gq);
    gather_kernel<<<gat_blocks, 256, 0, stream>>>(gq, rowptr, csr, agg);
    transform_kernel<<<tr_blocks, 256, 0, stream>>>(agg, dinv, b1, W2, gq);
    gather_kernel<<<gat_blocks, 256, 0, stream>>>(gq, rowptr, csr, agg);
    transform_kernel<<<tr_blocks, 256, 0, stream>>>(agg, dinv, b2, W3, gq);
    gather_kernel<<<gat_blocks, 256, 0, stream>>>(gq, rowptr, csr, agg);
    final_kernel<<<tr_blocks, 256, 0, stream>>>(agg, dinv, b3, Wm1, bm1, Wm2, bm2, out);
}

// Round 7
// 397.013 us; speedup vs baseline: 1.6284x; 1.3446x over previous
//
#include <hip/hip_runtime.h>
#include <hip/hip_fp16.h>
#include <math.h>

#define N_NODES 100000
#define N_EDGES 1600000
#define EP (N_EDGES + N_NODES)   // edges incl self-loops = 1,700,000
#define HID 64
#define SCAN_B 1024
#define NB ((N_NODES + SCAN_B - 1) / SCAN_B)   // 98 blocks
#define NPN 8    // nodes per wave (gather)       100000 % (4*8) == 0 -> exact grid
#define NPT 8    // nodes per wave (transform)

// ---------------- preamble: degree count + per-edge rank (atomic return) ----------------

__global__ void count4_kernel(const int* __restrict__ dst, int* __restrict__ deg,
                              int* __restrict__ rank) {
    int t = blockIdx.x * blockDim.x + threadIdx.x;
    if (t < N_EDGES / 4) {
        int4 d4 = ((const int4*)dst)[t];
        int4 r;
        r.x = atomicAdd(&deg[d4.x], 1);
        r.y = atomicAdd(&deg[d4.y], 1);
        r.z = atomicAdd(&deg[d4.z], 1);
        r.w = atomicAdd(&deg[d4.w], 1);
        ((int4*)rank)[t] = r;
    }
}

// ---------------- scan over (deg+1) (+ fused dinv) ----------------

__global__ void scan_block_kernel(const int* __restrict__ deg, int* __restrict__ rowptr,
                                  int* __restrict__ bsum, float* __restrict__ dinv) {
    __shared__ int wsum[16];
    int tid = threadIdx.x, lane = tid & 63, wid = tid >> 6;
    int i = blockIdx.x * SCAN_B + tid;
    int v = (i < N_NODES) ? deg[i] : 0;
    int x = (i < N_NODES) ? (v + 1) : 0;   // +1 self-loop slot
#pragma unroll
    for (int off = 1; off < 64; off <<= 1) {
        int y = __shfl_up(x, off, 64);
        if (lane >= off) x += y;
    }
    if (lane == 63) wsum[wid] = x;
    __syncthreads();
    if (tid == 0) {
        int s = 0;
#pragma unroll
        for (int j = 0; j < 16; ++j) { int t2 = wsum[j]; wsum[j] = s; s += t2; }
    }
    __syncthreads();
    int inc = wsum[wid] + x;
    if (i < N_NODES) {
        rowptr[i + 1] = inc;
        dinv[i] = rsqrtf((float)(v + 1));
    }
    if (tid == SCAN_B - 1) bsum[blockIdx.x] = inc;
}

__global__ void scan_bsum_kernel(int* __restrict__ bsum) {
    __shared__ int tmp[128];
    int t = threadIdx.x;
    tmp[t] = (t < NB) ? bsum[t] : 0;
    __syncthreads();
    for (int off = 1; off < 128; off <<= 1) {
        int v = (t >= off) ? tmp[t - off] : 0;
        __syncthreads();
        tmp[t] += v;
        __syncthreads();
    }
    if (t < NB) bsum[t] = (t == 0) ? 0 : tmp[t - 1];
}

// add block offsets + write self-loop edges + zero csr pad

__global__ void add_off_kernel(int* __restrict__ rowptr, const int* __restrict__ bsum,
                               int* __restrict__ csr_src) {
    int i = blockIdx.x * SCAN_B + threadIdx.x;
    if (i == 0) rowptr[0] = 0;
    if (i < N_NODES) {
        int rp1 = rowptr[i + 1] + bsum[blockIdx.x];
        rowptr[i + 1] = rp1;
        csr_src[rp1 - 1] = i;          // self-loop at end of node i's list
    }
    if (blockIdx.x == 0 && threadIdx.x < 64) csr_src[EP + threadIdx.x] = 0;  // pad
}

// ---------------- CSR fill: no atomics (rank precomputed) ----------------

__global__ void fill4_kernel(const int* __restrict__ src, const int* __restrict__ dst,
                             const int* __restrict__ rank, const int* __restrict__ rowptr,
                             int* __restrict__ csr_src) {
    int t = blockIdx.x * blockDim.x + threadIdx.x;
    if (t < N_EDGES / 4) {
        int4 s4 = ((const int4*)src)[t];
        int4 d4 = ((const int4*)dst)[t];
        int4 r4 = ((const int4*)rank)[t];
        csr_src[rowptr[d4.x] + r4.x] = s4.x;
        csr_src[rowptr[d4.y] + r4.y] = s4.y;
        csr_src[rowptr[d4.z] + r4.z] = s4.z;
        csr_src[rowptr[d4.w] + r4.w] = s4.w;
    }
}

// ---------------- layer 1: gf = fp16( dinv * (x @ W1) ), [N][64] ----------------

__global__ void layer1_kernel(const float* __restrict__ x, const float* __restrict__ W1,
                              const float* __restrict__ dinv, __half* __restrict__ gf) {
    int idx = blockIdx.x * blockDim.x + threadIdx.x;
    if (idx >= N_NODES * HID) return;
    int n = idx >> 6, c = idx & 63;
    float v = x[n * 3 + 0] * W1[c] + x[n * 3 + 1] * W1[HID + c]
            + x[n * 3 + 2] * W1[2 * HID + c];
    gf[idx] = __float2half(v * dinv[n]);
}

// ---------------- gather: full-feature pull, agg[n] = sum over CSR (incl self) ----------------
// 4 groups x 16 lanes; group g handles edges g, g+4, ...; lane slice p = 8B of the
// 128B fp16 feature row. Per node: 1 coalesced 64-index load + predicated
// independent feature loads (4 or 8 rounds; rare tail loop) + 2-step butterfly.

__global__ __launch_bounds__(256)
void gather_kernel(const __half* __restrict__ gf, const int* __restrict__ rowptr,
                   const int* __restrict__ csr, float* __restrict__ agg) {
    const int lane = threadIdx.x & 63, wid = threadIdx.x >> 6;
    const int g = lane >> 4, p = lane & 15;
    const int n0 = (blockIdx.x * 4 + wid) * NPN;
    int rp = rowptr[n0 + min(lane, NPN)];   // 9 lanes valid
    const uint2* gf2 = (const uint2*)gf;    // node s slice p -> gf2[s*16+p]
    int end_prev = __shfl(rp, 0, 64);
#pragma unroll
    for (int i = 0; i < NPN; ++i) {
        const int n = n0 + i;
        const int beg = end_prev;
        const int end = __shfl(rp, i + 1, 64);
        end_prev = end;
        const int cnt = end - beg;
        const int idxv = csr[beg + lane];   // safe: csr padded by 64
        float4 acc = make_float4(0.f, 0.f, 0.f, 0.f);
#pragma unroll
        for (int k = 0; k < 4; ++k) {
            int e = g + 4 * k;
            int s = __shfl(idxv, e, 64);
            uint2 u = gf2[(size_t)s * 16 + p];
            __half2 h0 = *(__half2*)&u.x, h1 = *(__half2*)&u.y;
            float2 a = __half22float2(h0), b = __half22float2(h1);
            if (e < cnt) { acc.x += a.x; acc.y += a.y; acc.z += b.x; acc.w += b.y; }
        }
        if (cnt > 16) {
#pragma unroll
            for (int k = 4; k < 8; ++k) {
                int e = g + 4 * k;
                int s = __shfl(idxv, e, 64);
                uint2 u = gf2[(size_t)s * 16 + p];
                __half2 h0 = *(__half2*)&u.x, h1 = *(__half2*)&u.y;
                float2 a = __half22float2(h0), b = __half22float2(h1);
                if (e < cnt) { acc.x += a.x; acc.y += a.y; acc.z += b.x; acc.w += b.y; }
            }
            if (cnt > 32) {          // rare (P ~ 2e-4 of nodes)
                for (int e = 32 + g; e < cnt; e += 4) {
                    int s = (e < 64) ? __shfl(idxv, e, 64) : csr[beg + e];
                    uint2 u = gf2[(size_t)s * 16 + p];
                    __half2 h0 = *(__half2*)&u.x, h1 = *(__half2*)&u.y;
                    float2 a = __half22float2(h0), b = __half22float2(h1);
                    acc.x += a.x; acc.y += a.y; acc.z += b.x; acc.w += b.y;
                }
            }
        }
        acc.x += __shfl_xor(acc.x, 16, 64);
        acc.y += __shfl_xor(acc.y, 16, 64);
        acc.z += __shfl_xor(acc.z, 16, 64);
        acc.w += __shfl_xor(acc.w, 16, 64);
        acc.x += __shfl_xor(acc.x, 32, 64);
        acc.y += __shfl_xor(acc.y, 32, 64);
        acc.z += __shfl_xor(acc.z, 32, 64);
        acc.w += __shfl_xor(acc.w, 32, 64);
        if (g == 0) ((float4*)(agg + (size_t)n * HID))[p] = acc;
    }
}

// ---------------- transform: hv = relu(di*agg + b); gf_out = fp16(di*(hv @ W)) ----------------

__global__ __launch_bounds__(256)
void transform_kernel(const float* __restrict__ agg, const float* __restrict__ dinv,
                      const float* __restrict__ bprev, const float* __restrict__ W,
                      __half* __restrict__ gf_out) {
    __shared__ float hvbuf[4][HID];
    const int lane = threadIdx.x & 63, wid = threadIdx.x >> 6;
    float4 Wr[16];
#pragma unroll
    for (int kk = 0; kk < 16; ++kk)
        Wr[kk] = make_float4(W[(4 * kk + 0) * HID + lane], W[(4 * kk + 1) * HID + lane],
                             W[(4 * kk + 2) * HID + lane], W[(4 * kk + 3) * HID + lane]);
    const float bl = bprev[lane];
    float* hvp = &hvbuf[wid][0];
    const float4* hp4 = (const float4*)hvp;
    const int n0 = (blockIdx.x * 4 + wid) * NPT;
#pragma unroll
    for (int i = 0; i < NPT; ++i) {
        int n = n0 + i;
        float a = agg[(size_t)n * HID + lane];
        float di = dinv[n];
        float hv = fmaxf(fmaf(di, a, bl), 0.0f);
        hvp[lane] = hv;
        float r0 = 0.f, r1 = 0.f, r2 = 0.f, r3 = 0.f;
#pragma unroll
        for (int kk = 0; kk < 16; ++kk) {
            float4 h4 = hp4[kk];   // same addr across lanes -> broadcast
            r0 = fmaf(h4.x, Wr[kk].x, r0);
            r1 = fmaf(h4.y, Wr[kk].y, r1);
            r2 = fmaf(h4.z, Wr[kk].z, r2);
            r3 = fmaf(h4.w, Wr[kk].w, r3);
        }
        gf_out[(size_t)n * HID + lane] = __float2half(di * ((r0 + r1) + (r2 + r3)));
    }
}

// ---------------- final: aggregate read + relu + MLP head + sigmoid ----------------

__global__ __launch_bounds__(256)
void final_kernel(const float* __restrict__ agg, const float* __restrict__ dinv,
                  const float* __restrict__ b3, const float* __restrict__ Wm1,
                  const float* __restrict__ bm1, const float* __restrict__ Wm2,
                  const float* __restrict__ bm2, float* __restrict__ out) {
    __shared__ float hvbuf[4][HID];
    const int lane = threadIdx.x & 63, wid = threadIdx.x >> 6;
    float4 Wr[16];
#pragma unroll
    for (int kk = 0; kk < 16; ++kk)
        Wr[kk] = make_float4(Wm1[(4 * kk + 0) * HID + lane], Wm1[(4 * kk + 1) * HID + lane],
                             Wm1[(4 * kk + 2) * HID + lane], Wm1[(4 * kk + 3) * HID + lane]);
    const float bl = b3[lane];
    const float bm1l = bm1[lane];
    const float wm2l = Wm2[lane];
    const float bm20 = bm2[0];
    float* hvp = &hvbuf[wid][0];
    const float4* hp4 = (const float4*)hvp;
    const int n0 = (blockIdx.x * 4 + wid) * NPT;
#pragma unroll
    for (int i = 0; i < NPT; ++i) {
        int n = n0 + i;
        float a = agg[(size_t)n * HID + lane];
        float di = dinv[n];
        float hv = fmaxf(fmaf(di, a, bl), 0.0f);
        hvp[lane] = hv;
        float r0 = 0.f, r1 = 0.f, r2 = 0.f, r3 = 0.f;
#pragma unroll
        for (int kk = 0; kk < 16; ++kk) {
            float4 h4 = hp4[kk];
            r0 = fmaf(h4.x, Wr[kk].x, r0);
            r1 = fmaf(h4.y, Wr[kk].y, r1);
            r2 = fmaf(h4.z, Wr[kk].z, r2);
            r3 = fmaf(h4.w, Wr[kk].w, r3);
        }
        float m = fmaxf(((r0 + r1) + (r2 + r3)) + bm1l, 0.0f);
        float s = m * wm2l;
#pragma unroll
        for (int off = 32; off > 0; off >>= 1) s += __shfl_down(s, off, 64);
        if (lane == 0) out[n] = 1.0f / (1.0f + expf(-(s + bm20)));
    }
}

// ---------------- launch ----------------

extern "C" void kernel_launch(void* const* d_in, const int* in_sizes, int n_in,
                              void* d_out, int out_size, void* d_ws, size_t ws_size,
                              hipStream_t stream) {
    const float* x   = (const float*)d_in[0];
    const int*   ei  = (const int*)d_in[1];
    const float* W1  = (const float*)d_in[2];
    const float* b1  = (const float*)d_in[3];
    const float* W2  = (const float*)d_in[4];
    const float* b2  = (const float*)d_in[5];
    const float* W3  = (const float*)d_in[6];
    const float* b3  = (const float*)d_in[7];
    const float* Wm1 = (const float*)d_in[8];
    const float* bm1 = (const float*)d_in[9];
    const float* Wm2 = (const float*)d_in[10];
    const float* bm2 = (const float*)d_in[11];
    float* out = (float*)d_out;

    const int* src = ei;
    const int* dst = ei + N_EDGES;

    char* ws = (char*)d_ws;
    size_t off = 0;
    auto alloc = [&](size_t bytes) { size_t o = off; off = (off + bytes + 255) & ~(size_t)255; return (void*)(ws + o); };
    int*    deg    = (int*)alloc(4ll * N_NODES);
    int*    rowptr = (int*)alloc(4ll * (N_NODES + 1));
    int*    bsum   = (int*)alloc(4ll * NB);
    int*    rank   = (int*)alloc(4ll * N_EDGES);
    int*    csr    = (int*)alloc(4ll * (EP + 64));       // +64 pad (zeros)
    float*  dinv   = (float*)alloc(4ll * N_NODES);
    __half* gf     = (__half*)alloc(2ll * N_NODES * HID);  // fp16 [N][64]
    float*  agg    = (float*)alloc(4ll * N_NODES * HID);   // fp32 [N][64]
    (void)ws_size;

    // --- CSR build (self-loops appended per node) ---
    hipMemsetAsync(deg, 0, 4ll * N_NODES, stream);
    count4_kernel<<<(N_EDGES / 4 + 255) / 256, 256, 0, stream>>>(dst, deg, rank);
    scan_block_kernel<<<NB, SCAN_B, 0, stream>>>(deg, rowptr, bsum, dinv);
    scan_bsum_kernel<<<1, 128, 0, stream>>>(bsum);
    add_off_kernel<<<NB, SCAN_B, 0, stream>>>(rowptr, bsum, csr);
    fill4_kernel<<<(N_EDGES / 4 + 255) / 256, 256, 0, stream>>>(src, dst, rank, rowptr, csr);

    // --- layers ---
    const int gblocks = N_NODES / (4 * NPN);   // 3125, exact
    const int tblocks = N_NODES / (4 * NPT);   // 3125, exact
    layer1_kernel<<<(N_NODES * HID + 255) / 256, 256, 0, stream>>>(x, W1, dinv, gf);
    gather_kernel<<<gblocks, 256, 0, stream>>>(gf, rowptr, csr, agg);
    transform_kernel<<<tblocks, 256, 0, stream>>>(agg, dinv, b1, W2, gf);
    gather_kernel<<<gblocks, 256, 0, stream>>>(gf, rowptr, csr, agg);
    transform_kernel<<<tblocks, 256, 0, stream>>>(agg, dinv, b2, W3, gf);
    gather_kernel<<<gblocks, 256, 0, stream>>>(gf, rowptr, csr, agg);
    final_kernel<<<tblocks, 256, 0, stream>>>(agg, dinv, b3, Wm1, bm1, Wm2, bm2, out);
}

// Round 8
// 349.999 us; speedup vs baseline: 1.8472x; 1.1343x over previous
//
#include <hip/hip_runtime.h>
#include <hip/hip_fp16.h>
#include <math.h>

#define N_NODES 100000
#define N_EDGES 1600000
#define EP (N_EDGES + N_NODES)   // edges incl self-loops = 1,700,000
#define HID 64
#define SCAN_B 1024
#define NB ((N_NODES + SCAN_B - 1) / SCAN_B)     // 98 blocks (node scan)
#define NCHUNK 256                               // pass-A chunks
#define CE (N_EDGES / NCHUNK)                    // 6250 edges per chunk (exact)
#define NBUCK 391                                // buckets of 256 keys: (99999>>8)+1
#define NHIST (NBUCK * NCHUNK)                   // 100096
#define NHB ((NHIST + SCAN_B - 1) / SCAN_B)      // 98 blocks (hist scan)
#define NPN 8    // nodes per wave (gather)
#define NPT 8    // nodes per wave (transform)

// ================= bucketed CSR build (no global atomics) =================

// A1: per-chunk LDS histogram over 391 coarse buckets -> h[bucket*NCHUNK + chunk]

__global__ __launch_bounds__(256)
void hist_kernel(const int* __restrict__ dst, int* __restrict__ h) {
    __shared__ int hist[NBUCK];
    const int tid = threadIdx.x, c = blockIdx.x;
    for (int b = tid; b < NBUCK; b += 256) hist[b] = 0;
    __syncthreads();
    for (int e = c * CE + tid; e < (c + 1) * CE; e += 256)
        atomicAdd(&hist[dst[e] >> 8], 1);
    __syncthreads();
    for (int b = tid; b < NBUCK; b += 256) h[b * NCHUNK + c] = hist[b];
}

// generic exclusive scan (3 kernels): out[0]=0, out[i+1]=inclusive(i)

__global__ void scang_block(const int* __restrict__ in, int* __restrict__ out,
                            int* __restrict__ bsum, int n) {
    __shared__ int wsum[16];
    int tid = threadIdx.x, lane = tid & 63, wid = tid >> 6;
    int i = blockIdx.x * SCAN_B + tid;
    int x = (i < n) ? in[i] : 0;
#pragma unroll
    for (int off = 1; off < 64; off <<= 1) {
        int y = __shfl_up(x, off, 64);
        if (lane >= off) x += y;
    }
    if (lane == 63) wsum[wid] = x;
    __syncthreads();
    if (tid == 0) {
        int s = 0;
#pragma unroll
        for (int j = 0; j < 16; ++j) { int t2 = wsum[j]; wsum[j] = s; s += t2; }
    }
    __syncthreads();
    int inc = wsum[wid] + x;
    if (i < n) out[i + 1] = inc;
    if (tid == SCAN_B - 1) bsum[blockIdx.x] = inc;
}

__global__ void scang_bsum(int* __restrict__ bsum, int nb) {   // nb <= 128
    __shared__ int tmp[128];
    int t = threadIdx.x;
    tmp[t] = (t < nb) ? bsum[t] : 0;
    __syncthreads();
    for (int off = 1; off < 128; off <<= 1) {
        int v = (t >= off) ? tmp[t - off] : 0;
        __syncthreads();
        tmp[t] += v;
        __syncthreads();
    }
    if (t < nb) bsum[t] = (t == 0) ? 0 : tmp[t - 1];
}

__global__ void scang_add(int* __restrict__ out, const int* __restrict__ bsum, int n) {
    int i = blockIdx.x * SCAN_B + threadIdx.x;
    if (i == 0) out[0] = 0;
    if (i < n) out[i + 1] += bsum[blockIdx.x];
}

// A2: scatter packed (dst,src) into bucket-major ebuf via LDS cursors

__global__ __launch_bounds__(256)
void scatter_kernel(const int* __restrict__ src, const int* __restrict__ dst,
                    const int* __restrict__ baseA, unsigned long long* __restrict__ ebuf) {
    __shared__ int cur[NBUCK];
    const int tid = threadIdx.x, c = blockIdx.x;
    for (int b = tid; b < NBUCK; b += 256) cur[b] = baseA[b * NCHUNK + c];
    __syncthreads();
    for (int e = c * CE + tid; e < (c + 1) * CE; e += 256) {
        int d = dst[e], s = src[e];
        int p = atomicAdd(&cur[d >> 8], 1);
        ebuf[p] = (unsigned long long)(unsigned)d | ((unsigned long long)(unsigned)s << 32);
    }
}

// B: per-bucket exact counts (LDS atomic-return) -> rank[], deg[] (non-atomic)

__global__ __launch_bounds__(256)
void rank_kernel(const unsigned long long* __restrict__ ebuf, const int* __restrict__ baseA,
                 int* __restrict__ rank, int* __restrict__ deg) {
    __shared__ int cnt[256];
    const int tid = threadIdx.x, b = blockIdx.x;
    cnt[tid] = 0;
    __syncthreads();
    const int R0 = baseA[b * NCHUNK], R1 = baseA[(b + 1) * NCHUNK];
    for (int pos = R0 + tid; pos < R1; pos += 256) {
        int d = (int)(unsigned)ebuf[pos];
        rank[pos] = atomicAdd(&cnt[d & 255], 1);
    }
    __syncthreads();
    int k = b * 256 + tid;
    if (k < N_NODES) deg[k] = cnt[tid];
}

// ---------------- node scan over (deg+1) (+ fused dinv) ----------------

__global__ void scan_block_kernel(const int* __restrict__ deg, int* __restrict__ rowptr,
                                  int* __restrict__ bsum, float* __restrict__ dinv) {
    __shared__ int wsum[16];
    int tid = threadIdx.x, lane = tid & 63, wid = tid >> 6;
    int i = blockIdx.x * SCAN_B + tid;
    int v = (i < N_NODES) ? deg[i] : 0;
    int x = (i < N_NODES) ? (v + 1) : 0;   // +1 self-loop slot
#pragma unroll
    for (int off = 1; off < 64; off <<= 1) {
        int y = __shfl_up(x, off, 64);
        if (lane >= off) x += y;
    }
    if (lane == 63) wsum[wid] = x;
    __syncthreads();
    if (tid == 0) {
        int s = 0;
#pragma unroll
        for (int j = 0; j < 16; ++j) { int t2 = wsum[j]; wsum[j] = s; s += t2; }
    }
    __syncthreads();
    int inc = wsum[wid] + x;
    if (i < N_NODES) {
        rowptr[i + 1] = inc;
        dinv[i] = rsqrtf((float)(v + 1));
    }
    if (tid == SCAN_B - 1) bsum[blockIdx.x] = inc;
}

// add block offsets + write self-loop edges + zero csr pad

__global__ void add_off_kernel(int* __restrict__ rowptr, const int* __restrict__ bsum,
                               int* __restrict__ csr_src) {
    int i = blockIdx.x * SCAN_B + threadIdx.x;
    if (i == 0) rowptr[0] = 0;
    if (i < N_NODES) {
        int rp1 = rowptr[i + 1] + bsum[blockIdx.x];
        rowptr[i + 1] = rp1;
        csr_src[rp1 - 1] = i;          // self-loop at end of node i's list
    }
    if (blockIdx.x == 0 && threadIdx.x < 64) csr_src[EP + threadIdx.x] = 0;  // pad
}

// fill: bucket-local rowptr reads + csr writes (L1/L2-hot), coalesced ebuf/rank reads

__global__ __launch_bounds__(256)
void fill_kernel(const unsigned long long* __restrict__ ebuf, const int* __restrict__ rank,
                 const int* __restrict__ rowptr, int* __restrict__ csr_src) {
    int pos = blockIdx.x * 256 + threadIdx.x;
    unsigned long long v = ebuf[pos];
    int d = (int)(unsigned)v, s = (int)(v >> 32);
    csr_src[rowptr[d] + rank[pos]] = s;
}

// ---------------- layer 1: gf = fp16( dinv * (x @ W1) ), [N][64] ----------------

__global__ void layer1_kernel(const float* __restrict__ x, const float* __restrict__ W1,
                              const float* __restrict__ dinv, __half* __restrict__ gf) {
    int idx = blockIdx.x * blockDim.x + threadIdx.x;
    if (idx >= N_NODES * HID) return;
    int n = idx >> 6, c = idx & 63;
    float v = x[n * 3 + 0] * W1[c] + x[n * 3 + 1] * W1[HID + c]
            + x[n * 3 + 2] * W1[2 * HID + c];
    gf[idx] = __float2half(v * dinv[n]);
}

// ---------------- gather: full-feature pull; 8 nodes' index vectors preloaded ----------------

__global__ __launch_bounds__(256)
void gather_kernel(const __half* __restrict__ gf, const int* __restrict__ rowptr,
                   const int* __restrict__ csr, float* __restrict__ agg) {
    const int lane = threadIdx.x & 63, wid = threadIdx.x >> 6;
    const int g = lane >> 4, p = lane & 15;
    const int n0 = (blockIdx.x * 4 + wid) * NPN;
    int rp = rowptr[n0 + min(lane, NPN)];   // 9 lanes valid
    const uint2* gf2 = (const uint2*)gf;    // node s slice p -> gf2[s*16+p]
    int begv[NPN], cntv[NPN], idxv[NPN];
    int end_prev = __shfl(rp, 0, 64);
#pragma unroll
    for (int i = 0; i < NPN; ++i) {         // 8 independent index loads in flight
        int end = __shfl(rp, i + 1, 64);
        begv[i] = end_prev;
        cntv[i] = end - end_prev;
        end_prev = end;
        idxv[i] = csr[begv[i] + lane];      // safe: csr padded by 64
    }
#pragma unroll
    for (int i = 0; i < NPN; ++i) {
        const int n = n0 + i;
        const int cnt = cntv[i], beg = begv[i], iv = idxv[i];
        float4 acc = make_float4(0.f, 0.f, 0.f, 0.f);
#pragma unroll
        for (int k = 0; k < 4; ++k) {
            int e = g + 4 * k;
            int s = __shfl(iv, e, 64);
            uint2 u = gf2[(size_t)s * 16 + p];
            __half2 h0 = *(__half2*)&u.x, h1 = *(__half2*)&u.y;
            float2 a = __half22float2(h0), b = __half22float2(h1);
            if (e < cnt) { acc.x += a.x; acc.y += a.y; acc.z += b.x; acc.w += b.y; }
        }
        if (cnt > 16) {
#pragma unroll
            for (int k = 4; k < 8; ++k) {
                int e = g + 4 * k;
                int s = __shfl(iv, e, 64);
                uint2 u = gf2[(size_t)s * 16 + p];
                __half2 h0 = *(__half2*)&u.x, h1 = *(__half2*)&u.y;
                float2 a = __half22float2(h0), b = __half22float2(h1);
                if (e < cnt) { acc.x += a.x; acc.y += a.y; acc.z += b.x; acc.w += b.y; }
            }
            if (cnt > 32) {          // rare tail
                for (int e = 32 + g; e < cnt; e += 4) {
                    int s = (e < 64) ? __shfl(iv, e, 64) : csr[beg + e];
                    uint2 u = gf2[(size_t)s * 16 + p];
                    __half2 h0 = *(__half2*)&u.x, h1 = *(__half2*)&u.y;
                    float2 a = __half22float2(h0), b = __half22float2(h1);
                    acc.x += a.x; acc.y += a.y; acc.z += b.x; acc.w += b.y;
                }
            }
        }
        acc.x += __shfl_xor(acc.x, 16, 64);
        acc.y += __shfl_xor(acc.y, 16, 64);
        acc.z += __shfl_xor(acc.z, 16, 64);
        acc.w += __shfl_xor(acc.w, 16, 64);
        acc.x += __shfl_xor(acc.x, 32, 64);
        acc.y += __shfl_xor(acc.y, 32, 64);
        acc.z += __shfl_xor(acc.z, 32, 64);
        acc.w += __shfl_xor(acc.w, 32, 64);
        if (g == 0) ((float4*)(agg + (size_t)n * HID))[p] = acc;
    }
}

// ---------------- transform: hv = relu(di*agg + b); gf_out = fp16(di*(hv @ W)) ----------------

__global__ __launch_bounds__(256)
void transform_kernel(const float* __restrict__ agg, const float* __restrict__ dinv,
                      const float* __restrict__ bprev, const float* __restrict__ W,
                      __half* __restrict__ gf_out) {
    __shared__ float hvbuf[4][HID];
    const int lane = threadIdx.x & 63, wid = threadIdx.x >> 6;
    float4 Wr[16];
#pragma unroll
    for (int kk = 0; kk < 16; ++kk)
        Wr[kk] = make_float4(W[(4 * kk + 0) * HID + lane], W[(4 * kk + 1) * HID + lane],
                             W[(4 * kk + 2) * HID + lane], W[(4 * kk + 3) * HID + lane]);
    const float bl = bprev[lane];
    float* hvp = &hvbuf[wid][0];
    const float4* hp4 = (const float4*)hvp;
    const int n0 = (blockIdx.x * 4 + wid) * NPT;
#pragma unroll
    for (int i = 0; i < NPT; ++i) {
        int n = n0 + i;
        float a = agg[(size_t)n * HID + lane];
        float di = dinv[n];
        float hv = fmaxf(fmaf(di, a, bl), 0.0f);
        hvp[lane] = hv;
        float r0 = 0.f, r1 = 0.f, r2 = 0.f, r3 = 0.f;
#pragma unroll
        for (int kk = 0; kk < 16; ++kk) {
            float4 h4 = hp4[kk];   // same addr across lanes -> broadcast
            r0 = fmaf(h4.x, Wr[kk].x, r0);
            r1 = fmaf(h4.y, Wr[kk].y, r1);
            r2 = fmaf(h4.z, Wr[kk].z, r2);
            r3 = fmaf(h4.w, Wr[kk].w, r3);
        }
        gf_out[(size_t)n * HID + lane] = __float2half(di * ((r0 + r1) + (r2 + r3)));
    }
}

// ---------------- final: aggregate read + relu + MLP head + sigmoid ----------------

__global__ __launch_bounds__(256)
void final_kernel(const float* __restrict__ agg, const float* __restrict__ dinv,
                  const float* __restrict__ b3, const float* __restrict__ Wm1,
                  const float* __restrict__ bm1, const float* __restrict__ Wm2,
                  const float* __restrict__ bm2, float* __restrict__ out) {
    __shared__ float hvbuf[4][HID];
    const int lane = threadIdx.x & 63, wid = threadIdx.x >> 6;
    float4 Wr[16];
#pragma unroll
    for (int kk = 0; kk < 16; ++kk)
        Wr[kk] = make_float4(Wm1[(4 * kk + 0) * HID + lane], Wm1[(4 * kk + 1) * HID + lane],
                             Wm1[(4 * kk + 2) * HID + lane], Wm1[(4 * kk + 3) * HID + lane]);
    const float bl = b3[lane];
    const float bm1l = bm1[lane];
    const float wm2l = Wm2[lane];
    const float bm20 = bm2[0];
    float* hvp = &hvbuf[wid][0];
    const float4* hp4 = (const float4*)hvp;
    const int n0 = (blockIdx.x * 4 + wid) * NPT;
#pragma unroll
    for (int i = 0; i < NPT; ++i) {
        int n = n0 + i;
        float a = agg[(size_t)n * HID + lane];
        float di = dinv[n];
        float hv = fmaxf(fmaf(di, a, bl), 0.0f);
        hvp[lane] = hv;
        float r0 = 0.f, r1 = 0.f, r2 = 0.f, r3 = 0.f;
#pragma unroll
        for (int kk = 0; kk < 16; ++kk) {
            float4 h4 = hp4[kk];
            r0 = fmaf(h4.x, Wr[kk].x, r0);
            r1 = fmaf(h4.y, Wr[kk].y, r1);
            r2 = fmaf(h4.z, Wr[kk].z, r2);
            r3 = fmaf(h4.w, Wr[kk].w, r3);
        }
        float m = fmaxf(((r0 + r1) + (r2 + r3)) + bm1l, 0.0f);
        float s = m * wm2l;
#pragma unroll
        for (int off = 32; off > 0; off >>= 1) s += __shfl_down(s, off, 64);
        if (lane == 0) out[n] = 1.0f / (1.0f + expf(-(s + bm20)));
    }
}

// ---------------- launch ----------------

extern "C" void kernel_launch(void* const* d_in, const int* in_sizes, int n_in,
                              void* d_out, int out_size, void* d_ws, size_t ws_size,
                              hipStream_t stream) {
    const float* x   = (const float*)d_in[0];
    const int*   ei  = (const int*)d_in[1];
    const float* W1  = (const float*)d_in[2];
    const float* b1  = (const float*)d_in[3];
    const float* W2  = (const float*)d_in[4];
    const float* b2  = (const float*)d_in[5];
    const float* W3  = (const float*)d_in[6];
    const float* b3  = (const float*)d_in[7];
    const float* Wm1 = (const float*)d_in[8];
    const float* bm1 = (const float*)d_in[9];
    const float* Wm2 = (const float*)d_in[10];
    const float* bm2 = (const float*)d_in[11];
    float* out = (float*)d_out;

    const int* src = ei;
    const int* dst = ei + N_EDGES;

    char* ws = (char*)d_ws;
    size_t off = 0;
    auto alloc = [&](size_t bytes) { size_t o = off; off = (off + bytes + 255) & ~(size_t)255; return (void*)(ws + o); };
    int*    deg    = (int*)alloc(4ll * N_NODES);
    int*    rowptr = (int*)alloc(4ll * (N_NODES + 1));
    int*    bsumN  = (int*)alloc(4ll * NB);
    int*    bsumA  = (int*)alloc(4ll * NHB);
    int*    histA  = (int*)alloc(4ll * NHIST);
    int*    baseA  = (int*)alloc(4ll * (NHIST + 1));
    int*    csr    = (int*)alloc(4ll * (EP + 64));       // +64 pad (zeros)
    float*  dinv   = (float*)alloc(4ll * N_NODES);
    __half* gf     = (__half*)alloc(2ll * N_NODES * HID);  // fp16 [N][64]
    float*  agg    = (float*)alloc(4ll * N_NODES * HID);   // fp32 [N][64]
    // preamble-only buffers alias agg (preamble finishes before first gather)
    unsigned long long* ebuf = (unsigned long long*)agg;            // 12.8 MB
    int*    rank   = (int*)((char*)agg + 8ll * N_EDGES);            // 6.4 MB
    (void)ws_size;

    // --- CSR build: zero global atomics ---
    hist_kernel<<<NCHUNK, 256, 0, stream>>>(dst, histA);
    scang_block<<<NHB, SCAN_B, 0, stream>>>(histA, baseA, bsumA, NHIST);
    scang_bsum<<<1, 128, 0, stream>>>(bsumA, NHB);
    scang_add<<<NHB, SCAN_B, 0, stream>>>(baseA, bsumA, NHIST);
    scatter_kernel<<<NCHUNK, 256, 0, stream>>>(src, dst, baseA, ebuf);
    rank_kernel<<<NBUCK, 256, 0, stream>>>(ebuf, baseA, rank, deg);
    scan_block_kernel<<<NB, SCAN_B, 0, stream>>>(deg, rowptr, bsumN, dinv);
    scang_bsum<<<1, 128, 0, stream>>>(bsumN, NB);
    add_off_kernel<<<NB, SCAN_B, 0, stream>>>(rowptr, bsumN, csr);
    fill_kernel<<<N_EDGES / 256, 256, 0, stream>>>(ebuf, rank, rowptr, csr);

    // --- layers ---
    const int gblocks = N_NODES / (4 * NPN);   // 3125, exact
    const int tblocks = N_NODES / (4 * NPT);   // 3125, exact
    layer1_kernel<<<(N_NODES * HID + 255) / 256, 256, 0, stream>>>(x, W1, dinv, gf);
    gather_kernel<<<gblocks, 256, 0, stream>>>(gf, rowptr, csr, agg);
    transform_kernel<<<tblocks, 256, 0, stream>>>(agg, dinv, b1, W2, gf);
    gather_kernel<<<gblocks, 256, 0, stream>>>(gf, rowptr, csr, agg);
    transform_kernel<<<tblocks, 256, 0, stream>>>(agg, dinv, b2, W3, gf);
    gather_kernel<<<gblocks, 256, 0, stream>>>(gf, rowptr, csr, agg);
    final_kernel<<<tblocks, 256, 0, stream>>>(agg, dinv, b3, Wm1, bm1, Wm2, bm2, out);
}